// Round 10
// baseline (237.841 us; speedup 1.0000x reference)
//
#include <hip/hip_runtime.h>
#include <math.h>

// Problem constants (fixed by reference setup_inputs)
#define L0   4448   // flux length
#define L1P  278    // after conv1(stride4,pad7)->1112 then maxpool4
#define L2   139    // after conv2(stride2,pad3) on 278
#define NQ   8
#define NL   3
#define SD   256

// LDS word map (float S[5660] = 22640 B):
//  h1T  bf16[286][20]  words 0..2859    row = pooled pos + 4; rows 0..3, 282..285 zero
//  Wb   bf16[32][136]  words 2860..5035 conv2 weights, K'=k*16+ic, k=7 row zero
//  Wc1  bf16[16][32]   words 5036..5291 conv1 weights (sign-flipped), K'=1..15 taps
//  featU f32[256]      words 5292..5547 pool sums; s_U after proj1 (R4 invariant)
//  edgeL bf16[112]     words 5548..5603 flux[-8..103]  (idx<0 zero)
//  edgeR bf16[112]     words 5604..5659 flux[4400..4511] (idx>=4448 zero)
// Aliases into dead h1T after stage2: s_hidden w0..63, s_red w64..95,
//  s_q w96..103, s_hid2 w104..135, cre w256..511, cim w512..767.
// Stage2 X-overread (rows 286..294) lands in Wb region: garbage, masked by
// the j>138 zeroing in the epilogue (R7-verified pattern).
#define WB_EL   5720
#define WC1_EL  10072
#define FTW     5292
#define EDGL_EL 11096
#define EDGR_EL 11208

typedef __attribute__((ext_vector_type(4))) short short4v;
typedef __attribute__((ext_vector_type(8))) short short8;
typedef __attribute__((ext_vector_type(4))) float f32x4;
union FragU { short8 v; short4v h[2]; };

__device__ __forceinline__ short f2bf(float x) {   // fp32 -> bf16 (RNE)
    unsigned u = __float_as_uint(x);
    u += 0x7FFFu + ((u >> 16) & 1u);
    return (short)(u >> 16);
}

__device__ __forceinline__ short8 pack8(float4 a, float4 b) {
    short8 v;
    v[0] = f2bf(a.x); v[1] = f2bf(a.y); v[2] = f2bf(a.z); v[3] = f2bf(a.w);
    v[4] = f2bf(b.x); v[5] = f2bf(b.y); v[6] = f2bf(b.z); v[7] = f2bf(b.w);
    return v;
}

// CNOT-ring permutation (one layer of 8 CNOTs composed). Linear over GF(2).
constexpr int permsrc_c(int x) {
    for (int q = 7; q >= 0; --q) {
        int cb = 7 - q, tb = 7 - ((q + 1) & 7);
        x ^= ((x >> cb) & 1) << tb;
    }
    return x;
}
constexpr int P40 = permsrc_c(0x40);
constexpr int P80 = permsrc_c(0x80);
constexpr int PC0 = permsrc_c(0xC0);

__device__ __forceinline__ int permsrc(int x) {
    #pragma unroll
    for (int q = 7; q >= 0; --q) {
        int cb = 7 - q, tb = 7 - ((q + 1) & 7);
        x ^= ((x >> cb) & 1) << tb;
    }
    return x;
}

// Combined 2-qubit (bits 7 and 6) gate: out = (U0 on bit7)(U1 on bit6) in.
__device__ __forceinline__ void apply2(const float* __restrict__ U0,
                                       const float* __restrict__ U1,
                                       int a7, int a6,
                                       const float vr[4], const float vi[4],
                                       float& re, float& im)
{
    float nr = 0.0f, ni = 0.0f;
    #pragma unroll
    for (int m7 = 0; m7 < 2; ++m7) {
        const float ur0 = U0[(a7 * 2 + (a7 ^ m7)) * 2];
        const float ui0 = U0[(a7 * 2 + (a7 ^ m7)) * 2 + 1];
        #pragma unroll
        for (int m6 = 0; m6 < 2; ++m6) {
            const float ur1 = U1[(a6 * 2 + (a6 ^ m6)) * 2];
            const float ui1 = U1[(a6 * 2 + (a6 ^ m6)) * 2 + 1];
            const float cr = ur0 * ur1 - ui0 * ui1;
            const float ci = ur0 * ui1 + ui0 * ur1;
            const int   id = m7 * 2 + m6;
            nr += cr * vr[id] - ci * vi[id];
            ni += cr * vi[id] + ci * vr[id];
        }
    }
    re = nr; im = ni;
}

__global__ __launch_bounds__(256, 4)
void aec_fused_kernel(const float* __restrict__ flux,
                      const float* __restrict__ scalars,
                      const float* __restrict__ conv1_w,
                      const float* __restrict__ bn1_g, const float* __restrict__ bn1_b,
                      const float* __restrict__ conv2_w,
                      const float* __restrict__ bn2_g, const float* __restrict__ bn2_b,
                      const float* __restrict__ proj_w1, const float* __restrict__ proj_b1,
                      const float* __restrict__ proj_w2, const float* __restrict__ proj_b2,
                      const float* __restrict__ qw,
                      const float* __restrict__ head_w1, const float* __restrict__ head_b1,
                      const float* __restrict__ head_bn_g, const float* __restrict__ head_bn_b,
                      const float* __restrict__ head_w2, const float* __restrict__ head_b2,
                      float* __restrict__ out)
{
    const int b   = blockIdx.x;
    const int tid = threadIdx.x;
    const float* frow = flux + (size_t)b * L0;

    __shared__ __align__(16) float S[5660];

    float* s_hidden = S;
    float* s_red    = S + 64;
    float* s_q      = S + 96;
    float* s_hid2   = S + 104;
    float* s_cre    = S + 256;
    float* s_cim    = S + 512;
    float* featU    = S + FTW;
    float* s_U      = S + FTW;      // gates overwrite featU AFTER proj1 (R4 invariant)

    const float BN_RSQ = 0.9999950000374997f;     // 1/sqrt(1+1e-5)

    // ---------------- stage 0: zeros + weight matrices + edge staging ----------
    featU[tid] = 0.0f;
    if (tid < 40)       S[tid] = 0.0f;            // h1T rows 0..3
    else if (tid < 80)  S[2780 + tid] = 0.0f;     // h1T rows 282..285
    {
        // Wc1[oc][k'] bf16: k'=0 zero, k'=1..15 = sgn*conv1_w[oc][k'-1], 16..31 zero.
        // Sign flip (exact) makes every effective bn1 scale >= 0 so maxpool can
        // run BEFORE the affine (monotone composition).
        const int oc = tid >> 4;
        const int q  = tid & 15;
        const float sgn = (bn1_g[oc] >= 0.0f) ? 1.0f : -1.0f;
        const int k0 = 2 * q, k1 = 2 * q + 1;
        const short e0 = (k0 >= 1 && k0 <= 15) ? f2bf(sgn * conv1_w[oc * 15 + k0 - 1]) : (short)0;
        const short e1 = (k1 <= 15)            ? f2bf(sgn * conv1_w[oc * 15 + k1 - 1]) : (short)0;
        const unsigned pk = (unsigned short)e0 | ((unsigned)(unsigned short)e1 << 16);
        *(unsigned*)((short*)S + WC1_EL + oc * 32 + 2 * q) = pk;
    }
    {
        // Wb[oc][K'=k*16+ic] bf16, row stride 136; k==7 row is the zero pad.
        const int oc = tid >> 3;
        const int k  = tid & 7;
        short tmp[16];
        #pragma unroll
        for (int ic = 0; ic < 16; ++ic)
            tmp[ic] = (k < 7) ? f2bf(conv2_w[oc * 112 + ic * 7 + k]) : (short)0;
        short8 w0, w1;
        #pragma unroll
        for (int e = 0; e < 8; ++e) { w0[e] = tmp[e]; w1[e] = tmp[8 + e]; }
        short8* dst = (short8*)((char*)S + (WB_EL + oc * 136 + k * 16) * 2);
        dst[0] = w0; dst[1] = w1;
    }
    // edge buffers for stage1 tiles 0 and 69 (zero-padded bf16 flux)
    if (tid < 112) {
        ((short*)S)[EDGL_EL + tid] = (tid >= 8) ? f2bf(frow[tid - 8]) : (short)0;
    } else if (tid < 224) {
        const int i = tid - 112;
        ((short*)S)[EDGR_EL + i] = (4400 + i < L0) ? f2bf(frow[4400 + i]) : (short)0;
    }
    __syncthreads();

    // ---------------- stage 1: conv1 as MFMA (transposed D) + pool + bn --------
    // D[j][oc] = X^T[16 j][32 k'] x Wc1^T[32][16 oc] (R9-verified).
    // A-frag: X[j = nt*16 + (lane&15)][k = quad*8+e] = flux[64nt+4col+8quad-8+e],
    // read DIRECTLY from global as two float4 (L1-resident row) + f2bf pack;
    // edge tiles (nt=0,69) use zero-padded LDS buffers — wave-uniform branches.
    // D: row (j_local) = quad*4+r, col (oc) = lane&15 -> lane's 4 regs are one
    // maxpool group: pool = 3 fmax, 0 shuffles.
    {
        const int lane = tid & 63;
        const int wid  = tid >> 6;
        const int col  = lane & 15;
        const int quad = lane >> 4;
        const short8 wfrag = *(const short8*)((const short*)S + WC1_EL + col * 32 + quad * 8);
        const float gsc = fabsf(bn1_g[col]) * BN_RSQ;
        const float gbt = bn1_b[col];
        const float* fbase = frow + 4 * col + 8 * quad - 8;
        const short* edl = (const short*)S + EDGL_EL + 4 * col + 8 * quad;
        const short* edr = (const short*)S + EDGR_EL + 8 + 4 * col + 8 * quad;

        for (int nt = wid; nt < 70; nt += 4) {
            FragU xu;
            if (nt == 0) {                       // wave-uniform (nt == wid)
                xu.h[0] = *(const short4v*)(edl);
                xu.h[1] = *(const short4v*)(edl + 4);
            } else if (nt == 69) {
                xu.h[0] = *(const short4v*)(edr);
                xu.h[1] = *(const short4v*)(edr + 4);
            } else {
                const float4* fp = (const float4*)(fbase + 64 * nt);
                xu.v = pack8(fp[0], fp[1]);
            }
            f32x4 acc = {0.f, 0.f, 0.f, 0.f};
            acc = __builtin_amdgcn_mfma_f32_16x16x32_bf16(xu.v, wfrag, acc, 0, 0, 0);
            const float m = fmaxf(fmaxf(acc[0], acc[1]), fmaxf(acc[2], acc[3]));
            const int p = nt * 4 + quad;         // pooled position
            if (p < L1P) {
                *((short*)S + (4 + p) * 20 + col) = f2bf(fmaxf(m * gsc + gbt, 0.0f));
            }
        }
    }
    __syncthreads();   // h1T complete; featU still pure pool sums

    // ---------------- stage 2: conv2 as MFMA (transposed D) + bn/relu + pool ----
    // (R9-verified) D[j][oc] = X^T[144 j][128] x Wb^T[128][32 oc]; lane's 4 regs
    // = 4 consecutive j -> bin partials in VALU, 2 shfl per accumulator.
    {
        const int lane = tid & 63;
        const int wid  = tid >> 6;
        const int col  = lane & 15;
        const int quad = lane >> 4;
        const short* h1s = (const short*)S;
        const char*  wbc = (const char*)((const short*)S + WB_EL);
        const float sc0 = bn2_g[col] * BN_RSQ,      bt0 = bn2_b[col];
        const float sc1 = bn2_g[col + 16] * BN_RSQ, bt1 = bn2_b[col + 16];

        for (int nt = wid; nt < 9; nt += 4) {
            const int n0 = nt * 16;
            f32x4 acc0 = {0.f,0.f,0.f,0.f}, acc1 = {0.f,0.f,0.f,0.f};
            #pragma unroll
            for (int kb = 0; kb < 4; ++kb) {
                const int k   = 2 * kb + (quad >> 1);
                const int ic0 = (quad & 1) * 8;
                const int row = 2 * (n0 + col) + 1 + k;
                FragU bu;
                bu.h[0] = *(const short4v*)(h1s + row * 20 + ic0);
                bu.h[1] = *(const short4v*)(h1s + row * 20 + ic0 + 4);
                const short8 a0 = *(const short8*)(wbc + (col * 136        + kb*32 + quad*8) * 2);
                const short8 a1 = *(const short8*)(wbc + ((16 + col) * 136 + kb*32 + quad*8) * 2);
                acc0 = __builtin_amdgcn_mfma_f32_16x16x32_bf16(bu.v, a0, acc0, 0, 0, 0);
                acc1 = __builtin_amdgcn_mfma_f32_16x16x32_bf16(bu.v, a1, acc1, 0, 0, 0);
            }
            const int   bA  = (8 * n0) / 139;
            const int   sB  = (139 * (bA + 1)) >> 3;      // j<=sB -> bA; j>=sB -> bA+1
            const float rcA = (bA == 2 || bA == 5) ? (1.0f/19.0f) : (1.0f/18.0f);
            const float rcB = (bA == 1 || bA == 4) ? (1.0f/19.0f) : (1.0f/18.0f);
            float va0 = 0.f, vb0 = 0.f, va1 = 0.f, vb1 = 0.f;
            #pragma unroll
            for (int r = 0; r < 4; ++r) {
                const int j = n0 + quad * 4 + r;
                float v0 = fmaxf(acc0[r] * sc0 + bt0, 0.0f);
                float v1 = fmaxf(acc1[r] * sc1 + bt1, 0.0f);
                if (j > 138) { v0 = 0.0f; v1 = 0.0f; }
                if (j <= sB) { va0 += v0; va1 += v1; }
                if (j >= sB) { vb0 += v0; vb1 += v1; }
            }
            va0 += __shfl_xor(va0, 16, 64); va0 += __shfl_xor(va0, 32, 64);
            va1 += __shfl_xor(va1, 16, 64); va1 += __shfl_xor(va1, 32, 64);
            vb0 += __shfl_xor(vb0, 16, 64); vb0 += __shfl_xor(vb0, 32, 64);
            vb1 += __shfl_xor(vb1, 16, 64); vb1 += __shfl_xor(vb1, 32, 64);
            if (quad == 0) {
                atomicAdd(&featU[col * 8 + bA],        va0 * rcA);
                atomicAdd(&featU[(col + 16) * 8 + bA], va1 * rcA);
                if (bA < 7) {
                    atomicAdd(&featU[col * 8 + bA + 1],        vb0 * rcB);
                    atomicAdd(&featU[(col + 16) * 8 + bA + 1], vb1 * rcB);
                }
            }
        }
    }
    __syncthreads();

    // ---------------- proj1 (256 -> 64), relu ----------------
    {
        const int o = tid >> 2, s = tid & 3;
        const float4* wg = (const float4*)(proj_w1 + 64 * tid);   // == o*256 + s*64
        const float4* xf = (const float4*)(featU + 64 * s);
        float acc = 0.0f;
        #pragma unroll
        for (int t = 0; t < 16; ++t) {
            float4 w4 = wg[t], x4 = xf[t];
            acc += w4.x * x4.x + w4.y * x4.y + w4.z * x4.z + w4.w * x4.w;
        }
        acc += __shfl_down(acc, 2, 64);
        acc += __shfl_down(acc, 1, 64);
        if (s == 0) s_hidden[o] = fmaxf(acc + proj_b1[o], 0.0f);
    }
    __syncthreads();

    // gate matrices into featU (feat consumed — only safe place, R4 invariant);
    // published by the __syncthreads() inside the normalize sequence below.
    if (tid < NL * NQ) {
        float phi = qw[tid * 3 + 0], th = qw[tid * 3 + 1], om = qw[tid * 3 + 2];
        float ch = cosf(0.5f * th), sh = sinf(0.5f * th);
        float a  = 0.5f * (phi + om), bb = 0.5f * (phi - om);
        float ca = cosf(a), sa = sinf(a), cb = cosf(bb), sb = sinf(bb);
        float* U = &s_U[tid * 8];
        U[0] =  ca * ch; U[1] = -sa * ch;   // U00
        U[2] = -cb * sh; U[3] = -sb * sh;   // U01
        U[4] =  cb * sh; U[5] = -sb * sh;   // U10
        U[6] =  ca * ch; U[7] =  sa * ch;   // U11
    }

    // ---------------- proj2 (64 -> 256) + L2 normalize ----------------
    float re, im;
    {
        const float4* wg = (const float4*)(proj_w2 + 64 * tid);
        const float4* hf = (const float4*)s_hidden;
        float acc = proj_b2[tid];
        #pragma unroll
        for (int t = 0; t < 16; ++t) {
            float4 w4 = wg[t], x4 = hf[t];
            acc += w4.x * x4.x + w4.y * x4.y + w4.z * x4.z + w4.w * x4.w;
        }
        float ss = acc * acc;
        #pragma unroll
        for (int off = 32; off >= 1; off >>= 1) ss += __shfl_xor(ss, off, 64);
        if ((tid & 63) == 0) s_red[tid >> 6] = ss;
        __syncthreads();                           // also publishes s_U
        float sst = s_red[0] + s_red[1] + s_red[2] + s_red[3];
        float n   = sqrtf(sst);
        float inv = 1.0f / fmaxf(n, 1e-12f);
        float xi  = acc * inv;
        if (n * inv < 1e-8f) xi = 0.0625f;        // uniform 1/sqrt(256)
        re = xi; im = 0.0f;
    }

    // ---------------- quantum circuit ----------------
    const int a7 = (tid >> 7) & 1, a6 = (tid >> 6) & 1;
    const int sP = permsrc(tid);

    s_cre[tid] = re; s_cim[tid] = im;
    __syncthreads();
    {
        float vr[4], vi[4];
        vr[0] = re;                vi[0] = im;
        vr[1] = s_cre[tid ^ 0x40]; vi[1] = s_cim[tid ^ 0x40];
        vr[2] = s_cre[tid ^ 0x80]; vi[2] = s_cim[tid ^ 0x80];
        vr[3] = s_cre[tid ^ 0xC0]; vi[3] = s_cim[tid ^ 0xC0];
        __syncthreads();
        apply2(&s_U[0], &s_U[8], a7, a6, vr, vi, re, im);
    }

    #pragma unroll
    for (int l = 0; l < NL; ++l) {
        #pragma unroll
        for (int q = 2; q < NQ; ++q) {
            const float* U = &s_U[(l * NQ + q) * 8];
            const float u00r = U[0], u00i = U[1], u01r = U[2], u01i = U[3];
            const float u10r = U[4], u10i = U[5], u11r = U[6], u11i = U[7];
            const int bp = 7 - q;
            const float pre = __shfl_xor(re, 1 << bp, 64);
            const float pim = __shfl_xor(im, 1 << bp, 64);
            const int bit = (tid >> bp) & 1;
            const float csr = bit ? u11r : u00r;
            const float csi = bit ? u11i : u00i;
            const float cpr = bit ? u10r : u01r;
            const float cpi = bit ? u10i : u01i;
            const float nr = csr * re - csi * im + cpr * pre - cpi * pim;
            const float ni = csr * im + csi * re + cpr * pim + cpi * pre;
            re = nr; im = ni;
        }
        s_cre[tid] = re; s_cim[tid] = im;
        __syncthreads();
        if (l < NL - 1) {
            float vr[4], vi[4];
            vr[0] = s_cre[sP];       vi[0] = s_cim[sP];
            vr[1] = s_cre[sP ^ P40]; vi[1] = s_cim[sP ^ P40];
            vr[2] = s_cre[sP ^ P80]; vi[2] = s_cim[sP ^ P80];
            vr[3] = s_cre[sP ^ PC0]; vi[3] = s_cim[sP ^ PC0];
            __syncthreads();
            apply2(&s_U[((l + 1) * NQ + 0) * 8], &s_U[((l + 1) * NQ + 1) * 8],
                   a7, a6, vr, vi, re, im);
        } else {
            re = s_cre[sP]; im = s_cim[sP];
            __syncthreads();
        }
    }

    // ---------------- Z expectations via Walsh-Hadamard butterfly --------------
    // <Z_q> = X[1<<(7-q)] where X[m] = sum_i (-1)^{popcount(m&i)} pr[i].
    // 6 in-wave butterfly stages give all per-wave coefficients; bits 6,7 are
    // wave-index signs combined through LDS. 6 shfl total (was 48).
    {
        const int lane = tid & 63;
        const int wv   = tid >> 6;
        float y = re * re + im * im;
        #pragma unroll
        for (int d = 0; d < 6; ++d) {
            const float p = __shfl_xor(y, 1 << d, 64);
            y = ((lane >> d) & 1) ? (p - y) : (y + p);
        }
        if (lane == 0) s_red[wv * 8] = y;
        else if ((lane & (lane - 1)) == 0) {
            const int slot = 32 - __clz(lane);    // log2(lane)+1, lane in {1..32}
            s_red[wv * 8 + slot] = y;
        }
        __syncthreads();
        if (tid < 8) {
            const int bp = 7 - tid;
            float v;
            if (bp < 6)
                v = s_red[bp + 1] + s_red[8 + bp + 1] + s_red[16 + bp + 1] + s_red[24 + bp + 1];
            else if (bp == 6)
                v = s_red[0] - s_red[8] + s_red[16] - s_red[24];
            else
                v = s_red[0] + s_red[8] - s_red[16] - s_red[24];
            s_q[tid] = v;
        }
        __syncthreads();
    }

    // ---------------- head ----------------
    if (tid < 32) {
        float acc = head_b1[tid];
        #pragma unroll
        for (int k = 0; k < 8; ++k) acc += head_w1[tid * 14 + k] * s_q[k];
        #pragma unroll
        for (int k = 0; k < 6; ++k) acc += head_w1[tid * 14 + 8 + k] * scalars[b * 6 + k];
        float h = fmaxf(acc * (head_bn_g[tid] * BN_RSQ) + head_bn_b[tid], 0.0f);
        s_hid2[tid] = h;
    }
    __syncthreads();
    if (tid < 3) {
        float acc = head_b2[tid];
        #pragma unroll
        for (int k = 0; k < 32; ++k) acc += head_w2[tid * 32 + k] * s_hid2[k];
        out[b * 3 + tid] = acc;
    }
}

extern "C" void kernel_launch(void* const* d_in, const int* in_sizes, int n_in,
                              void* d_out, int out_size, void* d_ws, size_t ws_size,
                              hipStream_t stream) {
    const float* flux      = (const float*)d_in[0];
    const float* scalars   = (const float*)d_in[1];
    const float* conv1_w   = (const float*)d_in[2];
    const float* bn1_g     = (const float*)d_in[3];
    const float* bn1_b     = (const float*)d_in[4];
    const float* conv2_w   = (const float*)d_in[5];
    const float* bn2_g     = (const float*)d_in[6];
    const float* bn2_b     = (const float*)d_in[7];
    const float* proj_w1   = (const float*)d_in[8];
    const float* proj_b1   = (const float*)d_in[9];
    const float* proj_w2   = (const float*)d_in[10];
    const float* proj_b2   = (const float*)d_in[11];
    const float* q_weights = (const float*)d_in[12];
    const float* head_w1   = (const float*)d_in[13];
    const float* head_b1   = (const float*)d_in[14];
    const float* head_bn_g = (const float*)d_in[15];
    const float* head_bn_b = (const float*)d_in[16];
    const float* head_w2   = (const float*)d_in[17];
    const float* head_b2   = (const float*)d_in[18];

    const int B = in_sizes[0] / L0;   // 4096

    aec_fused_kernel<<<dim3(B), dim3(256), 0, stream>>>(
        flux, scalars, conv1_w, bn1_g, bn1_b, conv2_w, bn2_g, bn2_b,
        proj_w1, proj_b1, proj_w2, proj_b2, q_weights,
        head_w1, head_b1, head_bn_g, head_bn_b, head_w2, head_b2,
        (float*)d_out);
}

// Round 11
// 228.740 us; speedup vs baseline: 1.0398x; 1.0398x over previous
//
#include <hip/hip_runtime.h>
#include <math.h>

// Problem constants (fixed by reference setup_inputs)
#define L0   4448   // flux length
#define L1P  278    // after conv1(stride4,pad7)->1112 then maxpool4
#define L2   139    // after conv2(stride2,pad3) on 278
#define NQ   8
#define NL   3
#define SD   256

// LDS element/word map (float S[7796] = 31184 B):
//  fxb  bf16[4496]      el 0..4495      flux[x] at el x+8; el 0..7 & 4456..4495 zero
//  h1T  bf16[286][20]   el 4496..10215  row = pooled pos + 4; rows 0..3, 282..285 zero
//                       (rows 0..3 zero also serve as fxb overread pad, el<=4507)
//  Wb   bf16[32][136]   el 10216..14567 conv2 weights, K' = k*16+ic, k=7 row zero
//  Wc1  bf16[16][32]    el 14568..15079 conv1 weights (sign-flipped), K'=1..15 taps
//  featU f32[256]       words 7540..7795 (pool sums; s_U after proj1 — R4 invariant)
// Aliases into dead fxb after stage1 (words 0..2247):
//  s_hidden w0..63, s_red w64..95, s_q w96..103, s_hid2 w104..135,
//  circuit buf0: cre w256..511, cim w512..767
//  circuit buf1: cre w768..1023, cim w1024..1279   (double buffer: R11)
#define H1T_EL 4496
#define WB_EL  10216
#define WC1_EL 14568
#define FTW    7540

typedef __attribute__((ext_vector_type(4))) short short4v;
typedef __attribute__((ext_vector_type(8))) short short8;
typedef __attribute__((ext_vector_type(4))) float f32x4;
union FragU { short8 v; short4v h[2]; };

__device__ __forceinline__ short f2bf(float x) {   // fp32 -> bf16 (RNE)
    unsigned u = __float_as_uint(x);
    u += 0x7FFFu + ((u >> 16) & 1u);
    return (short)(u >> 16);
}

// CNOT-ring permutation (one layer of 8 CNOTs composed). Linear over GF(2).
constexpr int permsrc_c(int x) {
    for (int q = 7; q >= 0; --q) {
        int cb = 7 - q, tb = 7 - ((q + 1) & 7);
        x ^= ((x >> cb) & 1) << tb;
    }
    return x;
}
constexpr int P40 = permsrc_c(0x40);
constexpr int P80 = permsrc_c(0x80);
constexpr int PC0 = permsrc_c(0xC0);

__device__ __forceinline__ int permsrc(int x) {
    #pragma unroll
    for (int q = 7; q >= 0; --q) {
        int cb = 7 - q, tb = 7 - ((q + 1) & 7);
        x ^= ((x >> cb) & 1) << tb;
    }
    return x;
}

// Combined 2-qubit (bits 7 and 6) gate: out = (U0 on bit7)(U1 on bit6) in.
__device__ __forceinline__ void apply2(const float* __restrict__ U0,
                                       const float* __restrict__ U1,
                                       int a7, int a6,
                                       const float vr[4], const float vi[4],
                                       float& re, float& im)
{
    float nr = 0.0f, ni = 0.0f;
    #pragma unroll
    for (int m7 = 0; m7 < 2; ++m7) {
        const float ur0 = U0[(a7 * 2 + (a7 ^ m7)) * 2];
        const float ui0 = U0[(a7 * 2 + (a7 ^ m7)) * 2 + 1];
        #pragma unroll
        for (int m6 = 0; m6 < 2; ++m6) {
            const float ur1 = U1[(a6 * 2 + (a6 ^ m6)) * 2];
            const float ui1 = U1[(a6 * 2 + (a6 ^ m6)) * 2 + 1];
            const float cr = ur0 * ur1 - ui0 * ui1;
            const float ci = ur0 * ui1 + ui0 * ur1;
            const int   id = m7 * 2 + m6;
            nr += cr * vr[id] - ci * vi[id];
            ni += cr * vi[id] + ci * vr[id];
        }
    }
    re = nr; im = ni;
}

__global__ __launch_bounds__(256, 4)
void aec_fused_kernel(const float* __restrict__ flux,
                      const float* __restrict__ scalars,
                      const float* __restrict__ conv1_w,
                      const float* __restrict__ bn1_g, const float* __restrict__ bn1_b,
                      const float* __restrict__ conv2_w,
                      const float* __restrict__ bn2_g, const float* __restrict__ bn2_b,
                      const float* __restrict__ proj_w1, const float* __restrict__ proj_b1,
                      const float* __restrict__ proj_w2, const float* __restrict__ proj_b2,
                      const float* __restrict__ qw,
                      const float* __restrict__ head_w1, const float* __restrict__ head_b1,
                      const float* __restrict__ head_bn_g, const float* __restrict__ head_bn_b,
                      const float* __restrict__ head_w2, const float* __restrict__ head_b2,
                      float* __restrict__ out)
{
    const int b   = blockIdx.x;
    const int tid = threadIdx.x;

    __shared__ __align__(16) float S[7796];

    float* s_hidden = S;
    float* s_red    = S + 64;
    float* s_q      = S + 96;
    float* s_hid2   = S + 104;
    float* featU    = S + FTW;
    float* s_U      = S + FTW;      // gates overwrite featU AFTER proj1 (R4 invariant)

    const float BN_RSQ = 0.9999950000374997f;     // 1/sqrt(1+1e-5)

    // ---------------- stage 0: zeros + weight matrices + flux staging ----------
    // (R9-verified body: LDS-staged bf16 flux beats global+convert — R10 lesson)
    featU[tid] = 0.0f;
    if (tid < 4)                    S[tid] = 0.0f;          // fxb el 0..7
    else if (tid < 64)              S[2224 + tid] = 0.0f;   // fxb tail + h1T rows 0..3
    else if (tid < 104)             S[5004 + tid] = 0.0f;   // h1T rows 282..285
    {
        // Wc1[oc][k'] bf16: k'=0 zero, k'=1..15 = sgn*conv1_w[oc][k'-1], 16..31 zero.
        // Sign flip (exact) makes every effective bn1 scale >= 0 so maxpool can
        // run BEFORE the affine (monotone composition).
        const int oc = tid >> 4;
        const int q  = tid & 15;
        const float sgn = (bn1_g[oc] >= 0.0f) ? 1.0f : -1.0f;
        const int k0 = 2 * q, k1 = 2 * q + 1;
        const short e0 = (k0 >= 1 && k0 <= 15) ? f2bf(sgn * conv1_w[oc * 15 + k0 - 1]) : (short)0;
        const short e1 = (k1 <= 15)            ? f2bf(sgn * conv1_w[oc * 15 + k1 - 1]) : (short)0;
        const unsigned pk = (unsigned short)e0 | ((unsigned)(unsigned short)e1 << 16);
        *(unsigned*)((short*)S + WC1_EL + oc * 32 + 2 * q) = pk;
    }
    {
        // Wb[oc][K'=k*16+ic] bf16, row stride 136; k==7 row is the zero pad.
        const int oc = tid >> 3;
        const int k  = tid & 7;
        short tmp[16];
        #pragma unroll
        for (int ic = 0; ic < 16; ++ic)
            tmp[ic] = (k < 7) ? f2bf(conv2_w[oc * 112 + ic * 7 + k]) : (short)0;
        short8 w0, w1;
        #pragma unroll
        for (int e = 0; e < 8; ++e) { w0[e] = tmp[e]; w1[e] = tmp[8 + e]; }
        short8* dst = (short8*)((char*)S + (WB_EL + oc * 136 + k * 16) * 2);
        dst[0] = w0; dst[1] = w1;
    }
    {
        // flux -> bf16 LDS (el x+8), coalesced float4 loads, aligned b64 stores
        const float4* fg = (const float4*)(flux + (size_t)b * L0);
        short* fx = (short*)S;
        for (int t = tid; t < L0 / 4; t += 256) {
            float4 v = fg[t];
            short4v pk;
            pk[0] = f2bf(v.x); pk[1] = f2bf(v.y); pk[2] = f2bf(v.z); pk[3] = f2bf(v.w);
            *(short4v*)(fx + 8 + 4 * t) = pk;
        }
    }
    __syncthreads();

    // ---------------- stage 1: conv1 as MFMA (transposed D) + pool + bn --------
    // (R9-verified) D[j][oc] = X^T[16 j][32 k'] x Wc1^T[32][16 oc].
    // Lane's 4 D-regs = 4 consecutive conv positions = one maxpool group:
    // pool = 3 fmax, 0 shuffles; one ds_write_b16 per pooled position.
    {
        const int lane = tid & 63;
        const int wid  = tid >> 6;
        const int col  = lane & 15;
        const int quad = lane >> 4;
        const short* fx = (const short*)S;
        const short8 wfrag = *(const short8*)((const short*)S + WC1_EL + col * 32 + quad * 8);
        const float gsc = fabsf(bn1_g[col]) * BN_RSQ;
        const float gbt = bn1_b[col];

        for (int nt = wid; nt < 70; nt += 4) {
            const int jl = nt * 16 + col;          // A's m-row = conv position
            FragU xu;
            xu.h[0] = *(const short4v*)(fx + 4 * jl + quad * 8);
            xu.h[1] = *(const short4v*)(fx + 4 * jl + quad * 8 + 4);
            f32x4 acc = {0.f, 0.f, 0.f, 0.f};
            acc = __builtin_amdgcn_mfma_f32_16x16x32_bf16(xu.v, wfrag, acc, 0, 0, 0);
            const float m = fmaxf(fmaxf(acc[0], acc[1]), fmaxf(acc[2], acc[3]));
            const int p = nt * 4 + quad;           // pooled position
            if (p < L1P) {
                *((short*)S + H1T_EL + (4 + p) * 20 + col) =
                    f2bf(fmaxf(m * gsc + gbt, 0.0f));
            }
        }
    }
    __syncthreads();   // h1T complete; featU still pure pool sums

    // ---------------- stage 2: conv2 as MFMA (transposed D) + bn/relu + pool ----
    // (R9-verified) D[j][oc] = X^T[144 j][128] x Wb^T[128][32 oc]; lane's 4 regs
    // = 4 consecutive j -> bin partials in VALU, 2 shfl per accumulator.
    {
        const int lane = tid & 63;
        const int wid  = tid >> 6;
        const int col  = lane & 15;
        const int quad = lane >> 4;
        const short* h1s = (const short*)S + H1T_EL;
        const char*  wbc = (const char*)((const short*)S + WB_EL);
        const float sc0 = bn2_g[col] * BN_RSQ,      bt0 = bn2_b[col];
        const float sc1 = bn2_g[col + 16] * BN_RSQ, bt1 = bn2_b[col + 16];

        for (int nt = wid; nt < 9; nt += 4) {
            const int n0 = nt * 16;
            f32x4 acc0 = {0.f,0.f,0.f,0.f}, acc1 = {0.f,0.f,0.f,0.f};
            #pragma unroll
            for (int kb = 0; kb < 4; ++kb) {
                const int k   = 2 * kb + (quad >> 1);
                const int ic0 = (quad & 1) * 8;
                const int row = 2 * (n0 + col) + 1 + k;
                FragU bu;
                bu.h[0] = *(const short4v*)(h1s + row * 20 + ic0);
                bu.h[1] = *(const short4v*)(h1s + row * 20 + ic0 + 4);
                const short8 a0 = *(const short8*)(wbc + (col * 136        + kb*32 + quad*8) * 2);
                const short8 a1 = *(const short8*)(wbc + ((16 + col) * 136 + kb*32 + quad*8) * 2);
                acc0 = __builtin_amdgcn_mfma_f32_16x16x32_bf16(bu.v, a0, acc0, 0, 0, 0);
                acc1 = __builtin_amdgcn_mfma_f32_16x16x32_bf16(bu.v, a1, acc1, 0, 0, 0);
            }
            const int   bA  = (8 * n0) / 139;
            const int   sB  = (139 * (bA + 1)) >> 3;      // j<=sB -> bA; j>=sB -> bA+1
            const float rcA = (bA == 2 || bA == 5) ? (1.0f/19.0f) : (1.0f/18.0f);
            const float rcB = (bA == 1 || bA == 4) ? (1.0f/19.0f) : (1.0f/18.0f);
            float va0 = 0.f, vb0 = 0.f, va1 = 0.f, vb1 = 0.f;
            #pragma unroll
            for (int r = 0; r < 4; ++r) {
                const int j = n0 + quad * 4 + r;
                float v0 = fmaxf(acc0[r] * sc0 + bt0, 0.0f);
                float v1 = fmaxf(acc1[r] * sc1 + bt1, 0.0f);
                if (j > 138) { v0 = 0.0f; v1 = 0.0f; }
                if (j <= sB) { va0 += v0; va1 += v1; }
                if (j >= sB) { vb0 += v0; vb1 += v1; }
            }
            va0 += __shfl_xor(va0, 16, 64); va0 += __shfl_xor(va0, 32, 64);
            va1 += __shfl_xor(va1, 16, 64); va1 += __shfl_xor(va1, 32, 64);
            vb0 += __shfl_xor(vb0, 16, 64); vb0 += __shfl_xor(vb0, 32, 64);
            vb1 += __shfl_xor(vb1, 16, 64); vb1 += __shfl_xor(vb1, 32, 64);
            if (quad == 0) {
                atomicAdd(&featU[col * 8 + bA],        va0 * rcA);
                atomicAdd(&featU[(col + 16) * 8 + bA], va1 * rcA);
                if (bA < 7) {
                    atomicAdd(&featU[col * 8 + bA + 1],        vb0 * rcB);
                    atomicAdd(&featU[(col + 16) * 8 + bA + 1], vb1 * rcB);
                }
            }
        }
    }
    __syncthreads();

    // ---------------- proj1 (256 -> 64), relu ----------------
    {
        const int o = tid >> 2, s = tid & 3;
        const float4* wg = (const float4*)(proj_w1 + 64 * tid);   // == o*256 + s*64
        const float4* xf = (const float4*)(featU + 64 * s);
        float acc = 0.0f;
        #pragma unroll
        for (int t = 0; t < 16; ++t) {
            float4 w4 = wg[t], x4 = xf[t];
            acc += w4.x * x4.x + w4.y * x4.y + w4.z * x4.z + w4.w * x4.w;
        }
        acc += __shfl_down(acc, 2, 64);
        acc += __shfl_down(acc, 1, 64);
        if (s == 0) s_hidden[o] = fmaxf(acc + proj_b1[o], 0.0f);
    }
    __syncthreads();

    // gate matrices into featU (feat consumed — only safe place, R4 invariant);
    // published by the __syncthreads() inside the normalize sequence below.
    if (tid < NL * NQ) {
        float phi = qw[tid * 3 + 0], th = qw[tid * 3 + 1], om = qw[tid * 3 + 2];
        float ch = cosf(0.5f * th), sh = sinf(0.5f * th);
        float a  = 0.5f * (phi + om), bb = 0.5f * (phi - om);
        float ca = cosf(a), sa = sinf(a), cb = cosf(bb), sb = sinf(bb);
        float* U = &s_U[tid * 8];
        U[0] =  ca * ch; U[1] = -sa * ch;   // U00
        U[2] = -cb * sh; U[3] = -sb * sh;   // U01
        U[4] =  cb * sh; U[5] = -sb * sh;   // U10
        U[6] =  ca * ch; U[7] =  sa * ch;   // U11
    }

    // ---------------- proj2 (64 -> 256) + L2 normalize ----------------
    float re, im;
    {
        const float4* wg = (const float4*)(proj_w2 + 64 * tid);
        const float4* hf = (const float4*)s_hidden;
        float acc = proj_b2[tid];
        #pragma unroll
        for (int t = 0; t < 16; ++t) {
            float4 w4 = wg[t], x4 = hf[t];
            acc += w4.x * x4.x + w4.y * x4.y + w4.z * x4.z + w4.w * x4.w;
        }
        float ss = acc * acc;
        #pragma unroll
        for (int off = 32; off >= 1; off >>= 1) ss += __shfl_xor(ss, off, 64);
        if ((tid & 63) == 0) s_red[tid >> 6] = ss;
        __syncthreads();                           // also publishes s_U
        float sst = s_red[0] + s_red[1] + s_red[2] + s_red[3];
        float n   = sqrtf(sst);
        float inv = 1.0f / fmaxf(n, 1e-12f);
        float xi  = acc * inv;
        if (n * inv < 1e-8f) xi = 0.0625f;        // uniform 1/sqrt(256)
        re = xi; im = 0.0f;
    }

    // ---------------- quantum circuit (double-buffered LDS state: R11) ---------
    // Write layer state to alternating buffers -> the write-after-read hazard
    // that required a second barrier per exchange disappears (4 syncs, was 8).
    const int a7 = (tid >> 7) & 1, a6 = (tid >> 6) & 1;
    const int sP = permsrc(tid);
    float* cre0 = S + 256;  float* cim0 = S + 512;
    float* cre1 = S + 768;  float* cim1 = S + 1024;

    cre0[tid] = re; cim0[tid] = im;
    __syncthreads();
    {
        float vr[4], vi[4];
        vr[0] = re;               vi[0] = im;
        vr[1] = cre0[tid ^ 0x40]; vi[1] = cim0[tid ^ 0x40];
        vr[2] = cre0[tid ^ 0x80]; vi[2] = cim0[tid ^ 0x80];
        vr[3] = cre0[tid ^ 0xC0]; vi[3] = cim0[tid ^ 0xC0];
        apply2(&s_U[0], &s_U[8], a7, a6, vr, vi, re, im);
    }

    #pragma unroll
    for (int l = 0; l < NL; ++l) {
        // gates q = 2..7 (bit positions 5..0): in-wave shuffles
        #pragma unroll
        for (int q = 2; q < NQ; ++q) {
            const float* U = &s_U[(l * NQ + q) * 8];
            const float u00r = U[0], u00i = U[1], u01r = U[2], u01i = U[3];
            const float u10r = U[4], u10i = U[5], u11r = U[6], u11i = U[7];
            const int bp = 7 - q;
            const float pre = __shfl_xor(re, 1 << bp, 64);
            const float pim = __shfl_xor(im, 1 << bp, 64);
            const int bit = (tid >> bp) & 1;
            const float csr = bit ? u11r : u00r;
            const float csi = bit ? u11i : u00i;
            const float cpr = bit ? u10r : u01r;
            const float cpi = bit ? u10i : u01i;
            const float nr = csr * re - csi * im + cpr * pre - cpi * pim;
            const float ni = csr * im + csi * re + cpr * pim + cpi * pre;
            re = nr; im = ni;
        }
        // CNOT-ring permutation fused with next layer's (bit7,bit6) gate;
        // alternate buffers: l=0 -> buf1, l=1 -> buf0, l=2 -> buf1.
        float* wr = (l & 1) ? cre0 : cre1;
        float* wi = (l & 1) ? cim0 : cim1;
        wr[tid] = re; wi[tid] = im;
        __syncthreads();
        if (l < NL - 1) {
            float vr[4], vi[4];
            vr[0] = wr[sP];       vi[0] = wi[sP];
            vr[1] = wr[sP ^ P40]; vi[1] = wi[sP ^ P40];
            vr[2] = wr[sP ^ P80]; vi[2] = wi[sP ^ P80];
            vr[3] = wr[sP ^ PC0]; vi[3] = wi[sP ^ PC0];
            apply2(&s_U[((l + 1) * NQ + 0) * 8], &s_U[((l + 1) * NQ + 1) * 8],
                   a7, a6, vr, vi, re, im);
        } else {
            re = wr[sP]; im = wi[sP];
        }
    }

    // ---------------- Z expectations via Walsh-Hadamard butterfly (R10-verified)
    // <Z_q> = X[1<<(7-q)], X[m] = sum_i (-1)^{popcount(m&i)} pr[i]. 6 in-wave
    // stages give all per-wave coefficients; bits 6,7 are wave-index signs.
    {
        const int lane = tid & 63;
        const int wv   = tid >> 6;
        float y = re * re + im * im;
        #pragma unroll
        for (int d = 0; d < 6; ++d) {
            const float p = __shfl_xor(y, 1 << d, 64);
            y = ((lane >> d) & 1) ? (p - y) : (y + p);
        }
        if (lane == 0) s_red[wv * 8] = y;
        else if ((lane & (lane - 1)) == 0) {
            const int slot = 32 - __clz(lane);    // log2(lane)+1, lane in {1..32}
            s_red[wv * 8 + slot] = y;
        }
        __syncthreads();
        if (tid < 8) {
            const int bp = 7 - tid;
            float v;
            if (bp < 6)
                v = s_red[bp + 1] + s_red[8 + bp + 1] + s_red[16 + bp + 1] + s_red[24 + bp + 1];
            else if (bp == 6)
                v = s_red[0] - s_red[8] + s_red[16] - s_red[24];
            else
                v = s_red[0] + s_red[8] - s_red[16] - s_red[24];
            s_q[tid] = v;
        }
        __syncthreads();
    }

    // ---------------- head ----------------
    if (tid < 32) {
        float acc = head_b1[tid];
        #pragma unroll
        for (int k = 0; k < 8; ++k) acc += head_w1[tid * 14 + k] * s_q[k];
        #pragma unroll
        for (int k = 0; k < 6; ++k) acc += head_w1[tid * 14 + 8 + k] * scalars[b * 6 + k];
        float h = fmaxf(acc * (head_bn_g[tid] * BN_RSQ) + head_bn_b[tid], 0.0f);
        s_hid2[tid] = h;
    }
    __syncthreads();
    if (tid < 3) {
        float acc = head_b2[tid];
        #pragma unroll
        for (int k = 0; k < 32; ++k) acc += head_w2[tid * 32 + k] * s_hid2[k];
        out[b * 3 + tid] = acc;
    }
}

extern "C" void kernel_launch(void* const* d_in, const int* in_sizes, int n_in,
                              void* d_out, int out_size, void* d_ws, size_t ws_size,
                              hipStream_t stream) {
    const float* flux      = (const float*)d_in[0];
    const float* scalars   = (const float*)d_in[1];
    const float* conv1_w   = (const float*)d_in[2];
    const float* bn1_g     = (const float*)d_in[3];
    const float* bn1_b     = (const float*)d_in[4];
    const float* conv2_w   = (const float*)d_in[5];
    const float* bn2_g     = (const float*)d_in[6];
    const float* bn2_b     = (const float*)d_in[7];
    const float* proj_w1   = (const float*)d_in[8];
    const float* proj_b1   = (const float*)d_in[9];
    const float* proj_w2   = (const float*)d_in[10];
    const float* proj_b2   = (const float*)d_in[11];
    const float* q_weights = (const float*)d_in[12];
    const float* head_w1   = (const float*)d_in[13];
    const float* head_b1   = (const float*)d_in[14];
    const float* head_bn_g = (const float*)d_in[15];
    const float* head_bn_b = (const float*)d_in[16];
    const float* head_w2   = (const float*)d_in[17];
    const float* head_b2   = (const float*)d_in[18];

    const int B = in_sizes[0] / L0;   // 4096

    aec_fused_kernel<<<dim3(B), dim3(256), 0, stream>>>(
        flux, scalars, conv1_w, bn1_g, bn1_b, conv2_w, bn2_g, bn2_b,
        proj_w1, proj_b1, proj_w2, proj_b2, q_weights,
        head_w1, head_b1, head_bn_g, head_bn_b, head_w2, head_b2,
        (float*)d_out);
}

// Round 12
// 226.431 us; speedup vs baseline: 1.0504x; 1.0102x over previous
//
#include <hip/hip_runtime.h>
#include <math.h>

// Problem constants (fixed by reference setup_inputs)
#define L0   4448   // flux length
#define L1P  278    // after conv1(stride4,pad7)->1112 then maxpool4
#define L2   139    // after conv2(stride2,pad3) on 278
#define NQ   8
#define NL   3
#define SD   256

// LDS element/word map (float S[7796] = 31184 B):
//  fxb  bf16[4496]      el 0..4495      flux[x] at el x+8; el 0..7 & 4456..4495 zero
//  h1T  bf16[286][20]   el 4496..10215  row = pooled pos + 4; rows 0..3, 282..285 zero
//                       (rows 0..3 zero also serve as fxb overread pad, el<=4507)
//  Wb   bf16[32][136]   el 10216..14567 conv2 weights, K' = k*16+ic, k=7 row zero
//  Wc1  bf16[16][32]    el 14568..15079 conv1 weights (sign-flipped), K'=1..15 taps
//  featU f32[256]       words 7540..7795 (pool sums; s_U after proj1 — R4 invariant)
// Aliases into dead fxb after stage1 (words 0..2247):
//  s_hidden w0..63, s_red w64..95, s_q w96..103, s_hid2 w104..135,
//  circuit buf0: cre w256..511, cim w512..767
//  circuit buf1: cre w768..1023, cim w1024..1279   (double buffer: R11)
#define H1T_EL 4496
#define WB_EL  10216
#define WC1_EL 14568
#define FTW    7540

typedef __attribute__((ext_vector_type(4))) short short4v;
typedef __attribute__((ext_vector_type(8))) short short8;
typedef __attribute__((ext_vector_type(4))) float f32x4;
union FragU { short8 v; short4v h[2]; };

__device__ __forceinline__ short f2bf(float x) {   // fp32 -> bf16 (RNE)
    unsigned u = __float_as_uint(x);
    u += 0x7FFFu + ((u >> 16) & 1u);
    return (short)(u >> 16);
}

__device__ __forceinline__ short8 pack8(float4 a, float4 b) {
    short8 v;
    v[0] = f2bf(a.x); v[1] = f2bf(a.y); v[2] = f2bf(a.z); v[3] = f2bf(a.w);
    v[4] = f2bf(b.x); v[5] = f2bf(b.y); v[6] = f2bf(b.z); v[7] = f2bf(b.w);
    return v;
}

// CNOT-ring permutation (one layer of 8 CNOTs composed). Linear over GF(2).
constexpr int permsrc_c(int x) {
    for (int q = 7; q >= 0; --q) {
        int cb = 7 - q, tb = 7 - ((q + 1) & 7);
        x ^= ((x >> cb) & 1) << tb;
    }
    return x;
}
constexpr int P40 = permsrc_c(0x40);
constexpr int P80 = permsrc_c(0x80);
constexpr int PC0 = permsrc_c(0xC0);

__device__ __forceinline__ int permsrc(int x) {
    #pragma unroll
    for (int q = 7; q >= 0; --q) {
        int cb = 7 - q, tb = 7 - ((q + 1) & 7);
        x ^= ((x >> cb) & 1) << tb;
    }
    return x;
}

// Combined 2-qubit (bits 7 and 6) gate: out = (U0 on bit7)(U1 on bit6) in.
__device__ __forceinline__ void apply2(const float* __restrict__ U0,
                                       const float* __restrict__ U1,
                                       int a7, int a6,
                                       const float vr[4], const float vi[4],
                                       float& re, float& im)
{
    float nr = 0.0f, ni = 0.0f;
    #pragma unroll
    for (int m7 = 0; m7 < 2; ++m7) {
        const float ur0 = U0[(a7 * 2 + (a7 ^ m7)) * 2];
        const float ui0 = U0[(a7 * 2 + (a7 ^ m7)) * 2 + 1];
        #pragma unroll
        for (int m6 = 0; m6 < 2; ++m6) {
            const float ur1 = U1[(a6 * 2 + (a6 ^ m6)) * 2];
            const float ui1 = U1[(a6 * 2 + (a6 ^ m6)) * 2 + 1];
            const float cr = ur0 * ur1 - ui0 * ui1;
            const float ci = ur0 * ui1 + ui0 * ur1;
            const int   id = m7 * 2 + m6;
            nr += cr * vr[id] - ci * vi[id];
            ni += cr * vi[id] + ci * vr[id];
        }
    }
    re = nr; im = ni;
}

__global__ __launch_bounds__(256, 4)
void aec_fused_kernel(const float* __restrict__ flux,
                      const float* __restrict__ scalars,
                      const float* __restrict__ conv1_w,
                      const float* __restrict__ bn1_g, const float* __restrict__ bn1_b,
                      const float* __restrict__ conv2_w,
                      const float* __restrict__ bn2_g, const float* __restrict__ bn2_b,
                      const float* __restrict__ proj_w1, const float* __restrict__ proj_b1,
                      const float* __restrict__ proj_w2, const float* __restrict__ proj_b2,
                      const float* __restrict__ qw,
                      const float* __restrict__ head_w1, const float* __restrict__ head_b1,
                      const float* __restrict__ head_bn_g, const float* __restrict__ head_bn_b,
                      const float* __restrict__ head_w2, const float* __restrict__ head_b2,
                      float* __restrict__ out)
{
    const int b   = blockIdx.x;
    const int tid = threadIdx.x;

    __shared__ __align__(16) float S[7796];

    float* s_hidden = S;
    float* s_red    = S + 64;
    float* s_q      = S + 96;
    float* s_hid2   = S + 104;
    float* featU    = S + FTW;
    float* s_U      = S + FTW;      // gates overwrite featU AFTER proj1 (R4 invariant)

    const float BN_RSQ = 0.9999950000374997f;     // 1/sqrt(1+1e-5)

    // ---------------- stage 0: zeros + weight matrices + flux staging ----------
    featU[tid] = 0.0f;
    if (tid < 4)                    S[tid] = 0.0f;          // fxb el 0..7
    else if (tid < 64)              S[2224 + tid] = 0.0f;   // fxb tail + h1T rows 0..3
    else if (tid < 104)             S[5004 + tid] = 0.0f;   // h1T rows 282..285
    {
        // Wc1[oc][k'] bf16: k'=0 zero, k'=1..15 = sgn*conv1_w[oc][k'-1], 16..31 zero.
        // Sign flip (exact) makes every effective bn1 scale >= 0 so maxpool can
        // run BEFORE the affine (monotone composition).
        const int oc = tid >> 4;
        const int q  = tid & 15;
        const float sgn = (bn1_g[oc] >= 0.0f) ? 1.0f : -1.0f;
        const int k0 = 2 * q, k1 = 2 * q + 1;
        const short e0 = (k0 >= 1 && k0 <= 15) ? f2bf(sgn * conv1_w[oc * 15 + k0 - 1]) : (short)0;
        const short e1 = (k1 <= 15)            ? f2bf(sgn * conv1_w[oc * 15 + k1 - 1]) : (short)0;
        const unsigned pk = (unsigned short)e0 | ((unsigned)(unsigned short)e1 << 16);
        *(unsigned*)((short*)S + WC1_EL + oc * 32 + 2 * q) = pk;
    }
    {
        // Wb[oc][K'=k*16+ic] bf16, row stride 136; k==7 row is the zero pad.
        const int oc = tid >> 3;
        const int k  = tid & 7;
        short tmp[16];
        #pragma unroll
        for (int ic = 0; ic < 16; ++ic)
            tmp[ic] = (k < 7) ? f2bf(conv2_w[oc * 112 + ic * 7 + k]) : (short)0;
        short8 w0, w1;
        #pragma unroll
        for (int e = 0; e < 8; ++e) { w0[e] = tmp[e]; w1[e] = tmp[8 + e]; }
        short8* dst = (short8*)((char*)S + (WB_EL + oc * 136 + k * 16) * 2);
        dst[0] = w0; dst[1] = w1;
    }
    {
        // flux -> bf16 LDS (el x+8): 8 els per iteration, b128 stores (R12).
        // 4448 = 556 * 8 exactly; el 8+8t -> byte 16+16t, 16B-aligned.
        const float4* fg = (const float4*)(flux + (size_t)b * L0);
        short* fx = (short*)S;
        for (int t = tid; t < 556; t += 256) {
            float4 v0 = fg[2 * t], v1 = fg[2 * t + 1];
            *(short8*)(fx + 8 + 8 * t) = pack8(v0, v1);
        }
    }
    __syncthreads();

    // ---------------- stage 1: conv1 as MFMA (transposed D) + pool + bn --------
    // (R9-verified) D[j][oc] = X^T[16 j][32 k'] x Wc1^T[32][16 oc].
    // Lane's 4 D-regs = 4 consecutive conv positions = one maxpool group:
    // pool = 3 fmax, 0 shuffles; one ds_write_b16 per pooled position.
    {
        const int lane = tid & 63;
        const int wid  = tid >> 6;
        const int col  = lane & 15;
        const int quad = lane >> 4;
        const short* fx = (const short*)S;
        const short8 wfrag = *(const short8*)((const short*)S + WC1_EL + col * 32 + quad * 8);
        const float gsc = fabsf(bn1_g[col]) * BN_RSQ;
        const float gbt = bn1_b[col];

        for (int nt = wid; nt < 70; nt += 4) {
            const int jl = nt * 16 + col;          // A's m-row = conv position
            FragU xu;
            xu.h[0] = *(const short4v*)(fx + 4 * jl + quad * 8);
            xu.h[1] = *(const short4v*)(fx + 4 * jl + quad * 8 + 4);
            f32x4 acc = {0.f, 0.f, 0.f, 0.f};
            acc = __builtin_amdgcn_mfma_f32_16x16x32_bf16(xu.v, wfrag, acc, 0, 0, 0);
            const float m = fmaxf(fmaxf(acc[0], acc[1]), fmaxf(acc[2], acc[3]));
            const int p = nt * 4 + quad;           // pooled position
            if (p < L1P) {
                *((short*)S + H1T_EL + (4 + p) * 20 + col) =
                    f2bf(fmaxf(m * gsc + gbt, 0.0f));
            }
        }
    }
    __syncthreads();   // h1T complete; featU still pure pool sums

    // ---------------- stage 2: conv2 as MFMA (transposed D) + bn/relu + pool ----
    // (R9-verified) D[j][oc] = X^T[144 j][128] x Wb^T[128][32 oc].
    // R12: weight fragments are nt-invariant -> hoisted out of the nt loop
    // (8 ds_read_b128 once instead of per tile; +32 VGPR, under the 128 cap).
    {
        const int lane = tid & 63;
        const int wid  = tid >> 6;
        const int col  = lane & 15;
        const int quad = lane >> 4;
        const short* h1s = (const short*)S + H1T_EL;
        const char*  wbc = (const char*)((const short*)S + WB_EL);
        const float sc0 = bn2_g[col] * BN_RSQ,      bt0 = bn2_b[col];
        const float sc1 = bn2_g[col + 16] * BN_RSQ, bt1 = bn2_b[col + 16];

        short8 wa0[4], wa1[4];
        #pragma unroll
        for (int kb = 0; kb < 4; ++kb) {
            wa0[kb] = *(const short8*)(wbc + (col * 136        + kb*32 + quad*8) * 2);
            wa1[kb] = *(const short8*)(wbc + ((16 + col) * 136 + kb*32 + quad*8) * 2);
        }

        for (int nt = wid; nt < 9; nt += 4) {
            const int n0 = nt * 16;
            f32x4 acc0 = {0.f,0.f,0.f,0.f}, acc1 = {0.f,0.f,0.f,0.f};
            #pragma unroll
            for (int kb = 0; kb < 4; ++kb) {
                const int k   = 2 * kb + (quad >> 1);
                const int ic0 = (quad & 1) * 8;
                const int row = 2 * (n0 + col) + 1 + k;
                FragU bu;
                bu.h[0] = *(const short4v*)(h1s + row * 20 + ic0);
                bu.h[1] = *(const short4v*)(h1s + row * 20 + ic0 + 4);
                acc0 = __builtin_amdgcn_mfma_f32_16x16x32_bf16(bu.v, wa0[kb], acc0, 0, 0, 0);
                acc1 = __builtin_amdgcn_mfma_f32_16x16x32_bf16(bu.v, wa1[kb], acc1, 0, 0, 0);
            }
            const int   bA  = (8 * n0) / 139;
            const int   sB  = (139 * (bA + 1)) >> 3;      // j<=sB -> bA; j>=sB -> bA+1
            const float rcA = (bA == 2 || bA == 5) ? (1.0f/19.0f) : (1.0f/18.0f);
            const float rcB = (bA == 1 || bA == 4) ? (1.0f/19.0f) : (1.0f/18.0f);
            float va0 = 0.f, vb0 = 0.f, va1 = 0.f, vb1 = 0.f;
            #pragma unroll
            for (int r = 0; r < 4; ++r) {
                const int j = n0 + quad * 4 + r;
                float v0 = fmaxf(acc0[r] * sc0 + bt0, 0.0f);
                float v1 = fmaxf(acc1[r] * sc1 + bt1, 0.0f);
                if (j > 138) { v0 = 0.0f; v1 = 0.0f; }
                if (j <= sB) { va0 += v0; va1 += v1; }
                if (j >= sB) { vb0 += v0; vb1 += v1; }
            }
            va0 += __shfl_xor(va0, 16, 64); va0 += __shfl_xor(va0, 32, 64);
            va1 += __shfl_xor(va1, 16, 64); va1 += __shfl_xor(va1, 32, 64);
            vb0 += __shfl_xor(vb0, 16, 64); vb0 += __shfl_xor(vb0, 32, 64);
            vb1 += __shfl_xor(vb1, 16, 64); vb1 += __shfl_xor(vb1, 32, 64);
            if (quad == 0) {
                atomicAdd(&featU[col * 8 + bA],        va0 * rcA);
                atomicAdd(&featU[(col + 16) * 8 + bA], va1 * rcA);
                if (bA < 7) {
                    atomicAdd(&featU[col * 8 + bA + 1],        vb0 * rcB);
                    atomicAdd(&featU[(col + 16) * 8 + bA + 1], vb1 * rcB);
                }
            }
        }
    }
    __syncthreads();

    // ---------------- proj1 (256 -> 64), relu ----------------
    {
        const int o = tid >> 2, s = tid & 3;
        const float4* wg = (const float4*)(proj_w1 + 64 * tid);   // == o*256 + s*64
        const float4* xf = (const float4*)(featU + 64 * s);
        float acc = 0.0f;
        #pragma unroll
        for (int t = 0; t < 16; ++t) {
            float4 w4 = wg[t], x4 = xf[t];
            acc += w4.x * x4.x + w4.y * x4.y + w4.z * x4.z + w4.w * x4.w;
        }
        acc += __shfl_down(acc, 2, 64);
        acc += __shfl_down(acc, 1, 64);
        if (s == 0) s_hidden[o] = fmaxf(acc + proj_b1[o], 0.0f);
    }
    __syncthreads();

    // gate matrices into featU (feat consumed — only safe place, R4 invariant);
    // published by the __syncthreads() inside the normalize sequence below.
    if (tid < NL * NQ) {
        float phi = qw[tid * 3 + 0], th = qw[tid * 3 + 1], om = qw[tid * 3 + 2];
        float ch = cosf(0.5f * th), sh = sinf(0.5f * th);
        float a  = 0.5f * (phi + om), bb = 0.5f * (phi - om);
        float ca = cosf(a), sa = sinf(a), cb = cosf(bb), sb = sinf(bb);
        float* U = &s_U[tid * 8];
        U[0] =  ca * ch; U[1] = -sa * ch;   // U00
        U[2] = -cb * sh; U[3] = -sb * sh;   // U01
        U[4] =  cb * sh; U[5] = -sb * sh;   // U10
        U[6] =  ca * ch; U[7] =  sa * ch;   // U11
    }

    // ---------------- proj2 (64 -> 256) + L2 normalize ----------------
    float re, im;
    {
        const float4* wg = (const float4*)(proj_w2 + 64 * tid);
        const float4* hf = (const float4*)s_hidden;
        float acc = proj_b2[tid];
        #pragma unroll
        for (int t = 0; t < 16; ++t) {
            float4 w4 = wg[t], x4 = hf[t];
            acc += w4.x * x4.x + w4.y * x4.y + w4.z * x4.z + w4.w * x4.w;
        }
        float ss = acc * acc;
        #pragma unroll
        for (int off = 32; off >= 1; off >>= 1) ss += __shfl_xor(ss, off, 64);
        if ((tid & 63) == 0) s_red[tid >> 6] = ss;
        __syncthreads();                           // also publishes s_U
        float sst = s_red[0] + s_red[1] + s_red[2] + s_red[3];
        float n   = sqrtf(sst);
        float inv = 1.0f / fmaxf(n, 1e-12f);
        float xi  = acc * inv;
        if (n * inv < 1e-8f) xi = 0.0625f;        // uniform 1/sqrt(256)
        re = xi; im = 0.0f;
    }

    // ---------------- quantum circuit (double-buffered LDS state: R11) ---------
    const int a7 = (tid >> 7) & 1, a6 = (tid >> 6) & 1;
    const int sP = permsrc(tid);
    float* cre0 = S + 256;  float* cim0 = S + 512;
    float* cre1 = S + 768;  float* cim1 = S + 1024;

    cre0[tid] = re; cim0[tid] = im;
    __syncthreads();
    {
        float vr[4], vi[4];
        vr[0] = re;               vi[0] = im;
        vr[1] = cre0[tid ^ 0x40]; vi[1] = cim0[tid ^ 0x40];
        vr[2] = cre0[tid ^ 0x80]; vi[2] = cim0[tid ^ 0x80];
        vr[3] = cre0[tid ^ 0xC0]; vi[3] = cim0[tid ^ 0xC0];
        apply2(&s_U[0], &s_U[8], a7, a6, vr, vi, re, im);
    }

    #pragma unroll
    for (int l = 0; l < NL; ++l) {
        // gates q = 2..7 (bit positions 5..0): in-wave shuffles
        #pragma unroll
        for (int q = 2; q < NQ; ++q) {
            const float* U = &s_U[(l * NQ + q) * 8];
            const float u00r = U[0], u00i = U[1], u01r = U[2], u01i = U[3];
            const float u10r = U[4], u10i = U[5], u11r = U[6], u11i = U[7];
            const int bp = 7 - q;
            const float pre = __shfl_xor(re, 1 << bp, 64);
            const float pim = __shfl_xor(im, 1 << bp, 64);
            const int bit = (tid >> bp) & 1;
            const float csr = bit ? u11r : u00r;
            const float csi = bit ? u11i : u00i;
            const float cpr = bit ? u10r : u01r;
            const float cpi = bit ? u10i : u01i;
            const float nr = csr * re - csi * im + cpr * pre - cpi * pim;
            const float ni = csr * im + csi * re + cpr * pim + cpi * pre;
            re = nr; im = ni;
        }
        // CNOT-ring permutation fused with next layer's (bit7,bit6) gate;
        // alternate buffers: l=0 -> buf1, l=1 -> buf0, l=2 -> buf1.
        float* wr = (l & 1) ? cre0 : cre1;
        float* wi = (l & 1) ? cim0 : cim1;
        wr[tid] = re; wi[tid] = im;
        __syncthreads();
        if (l < NL - 1) {
            float vr[4], vi[4];
            vr[0] = wr[sP];       vi[0] = wi[sP];
            vr[1] = wr[sP ^ P40]; vi[1] = wi[sP ^ P40];
            vr[2] = wr[sP ^ P80]; vi[2] = wi[sP ^ P80];
            vr[3] = wr[sP ^ PC0]; vi[3] = wi[sP ^ PC0];
            apply2(&s_U[((l + 1) * NQ + 0) * 8], &s_U[((l + 1) * NQ + 1) * 8],
                   a7, a6, vr, vi, re, im);
        } else {
            re = wr[sP]; im = wi[sP];
        }
    }

    // ---------------- Z expectations via Walsh-Hadamard butterfly (R10-verified)
    {
        const int lane = tid & 63;
        const int wv   = tid >> 6;
        float y = re * re + im * im;
        #pragma unroll
        for (int d = 0; d < 6; ++d) {
            const float p = __shfl_xor(y, 1 << d, 64);
            y = ((lane >> d) & 1) ? (p - y) : (y + p);
        }
        if (lane == 0) s_red[wv * 8] = y;
        else if ((lane & (lane - 1)) == 0) {
            const int slot = 32 - __clz(lane);    // log2(lane)+1, lane in {1..32}
            s_red[wv * 8 + slot] = y;
        }
        __syncthreads();
        if (tid < 8) {
            const int bp = 7 - tid;
            float v;
            if (bp < 6)
                v = s_red[bp + 1] + s_red[8 + bp + 1] + s_red[16 + bp + 1] + s_red[24 + bp + 1];
            else if (bp == 6)
                v = s_red[0] - s_red[8] + s_red[16] - s_red[24];
            else
                v = s_red[0] + s_red[8] - s_red[16] - s_red[24];
            s_q[tid] = v;
        }
        __syncthreads();
    }

    // ---------------- head ----------------
    if (tid < 32) {
        float acc = head_b1[tid];
        #pragma unroll
        for (int k = 0; k < 8; ++k) acc += head_w1[tid * 14 + k] * s_q[k];
        #pragma unroll
        for (int k = 0; k < 6; ++k) acc += head_w1[tid * 14 + 8 + k] * scalars[b * 6 + k];
        float h = fmaxf(acc * (head_bn_g[tid] * BN_RSQ) + head_bn_b[tid], 0.0f);
        s_hid2[tid] = h;
    }
    __syncthreads();
    if (tid < 3) {
        float acc = head_b2[tid];
        #pragma unroll
        for (int k = 0; k < 32; ++k) acc += head_w2[tid * 32 + k] * s_hid2[k];
        out[b * 3 + tid] = acc;
    }
}

extern "C" void kernel_launch(void* const* d_in, const int* in_sizes, int n_in,
                              void* d_out, int out_size, void* d_ws, size_t ws_size,
                              hipStream_t stream) {
    const float* flux      = (const float*)d_in[0];
    const float* scalars   = (const float*)d_in[1];
    const float* conv1_w   = (const float*)d_in[2];
    const float* bn1_g     = (const float*)d_in[3];
    const float* bn1_b     = (const float*)d_in[4];
    const float* conv2_w   = (const float*)d_in[5];
    const float* bn2_g     = (const float*)d_in[6];
    const float* bn2_b     = (const float*)d_in[7];
    const float* proj_w1   = (const float*)d_in[8];
    const float* proj_b1   = (const float*)d_in[9];
    const float* proj_w2   = (const float*)d_in[10];
    const float* proj_b2   = (const float*)d_in[11];
    const float* q_weights = (const float*)d_in[12];
    const float* head_w1   = (const float*)d_in[13];
    const float* head_b1   = (const float*)d_in[14];
    const float* head_bn_g = (const float*)d_in[15];
    const float* head_bn_b = (const float*)d_in[16];
    const float* head_w2   = (const float*)d_in[17];
    const float* head_b2   = (const float*)d_in[18];

    const int B = in_sizes[0] / L0;   // 4096

    aec_fused_kernel<<<dim3(B), dim3(256), 0, stream>>>(
        flux, scalars, conv1_w, bn1_g, bn1_b, conv2_w, bn2_g, bn2_b,
        proj_w1, proj_b1, proj_w2, proj_b2, q_weights,
        head_w1, head_b1, head_bn_g, head_bn_b, head_w2, head_b2,
        (float*)d_out);
}

// Round 13
// 225.053 us; speedup vs baseline: 1.0568x; 1.0061x over previous
//
#include <hip/hip_runtime.h>
#include <math.h>

// Problem constants (fixed by reference setup_inputs)
#define L0   4448   // flux length
#define L1P  278    // after conv1(stride4,pad7)->1112 then maxpool4
#define L2   139    // after conv2(stride2,pad3) on 278
#define NQ   8
#define NL   3
#define SD   256

// LDS element/word map (float S[7796] = 31184 B):
//  fxb  bf16[4496]      el 0..4495      flux[x] at el x+8; el 0..7 & 4456..4495 zero
//  h1T  bf16[286][20]   el 4496..10215  row = pooled pos + 4; rows 0..3, 282..285 zero
//                       (rows 0..3 zero also serve as fxb overread pad, el<=4507)
//  Wb   bf16[32][136]   el 10216..14567 conv2 weights, K' = k*16+ic, k=7 row zero
//  Wc1  bf16[16][32]    el 14568..15079 conv1 weights (sign-flipped), K'=1..15 taps
//  featU f32[256]       words 7540..7795 (pool sums; s_U after proj1 — R4 invariant)
// Aliases into dead fxb after stage1 (words 0..2247):
//  s_hidden w0..63, s_red w64..95, s_q w96..103,
//  amp re buffer w256..511, amp im / perm scratch w512..767
#define H1T_EL 4496
#define WB_EL  10216
#define WC1_EL 14568
#define FTW    7540

typedef __attribute__((ext_vector_type(4))) short short4v;
typedef __attribute__((ext_vector_type(8))) short short8;
typedef __attribute__((ext_vector_type(4))) float f32x4;
union FragU { short8 v; short4v h[2]; };

__device__ __forceinline__ short f2bf(float x) {   // fp32 -> bf16 (RNE)
    unsigned u = __float_as_uint(x);
    u += 0x7FFFu + ((u >> 16) & 1u);
    return (short)(u >> 16);
}

__device__ __forceinline__ short8 pack8(float4 a, float4 b) {
    short8 v;
    v[0] = f2bf(a.x); v[1] = f2bf(a.y); v[2] = f2bf(a.z); v[3] = f2bf(a.w);
    v[4] = f2bf(b.x); v[5] = f2bf(b.y); v[6] = f2bf(b.z); v[7] = f2bf(b.w);
    return v;
}

// CNOT-ring permutation (one layer of 8 CNOTs composed). Linear over GF(2).
constexpr int permsrc_c(int x) {
    for (int q = 7; q >= 0; --q) {
        int cb = 7 - q, tb = 7 - ((q + 1) & 7);
        x ^= ((x >> cb) & 1) << tb;
    }
    return x;
}
constexpr int P40 = permsrc_c(0x40);
constexpr int P80 = permsrc_c(0x80);
constexpr int PC0 = permsrc_c(0xC0);

__device__ __forceinline__ int permsrc(int x) {
    #pragma unroll
    for (int q = 7; q >= 0; --q) {
        int cb = 7 - q, tb = 7 - ((q + 1) & 7);
        x ^= ((x >> cb) & 1) << tb;
    }
    return x;
}

__global__ __launch_bounds__(256, 4)
void aec_fused_kernel(const float* __restrict__ flux,
                      const float* __restrict__ scalars,
                      const float* __restrict__ conv1_w,
                      const float* __restrict__ bn1_g, const float* __restrict__ bn1_b,
                      const float* __restrict__ conv2_w,
                      const float* __restrict__ bn2_g, const float* __restrict__ bn2_b,
                      const float* __restrict__ proj_w1, const float* __restrict__ proj_b1,
                      const float* __restrict__ proj_w2, const float* __restrict__ proj_b2,
                      const float* __restrict__ qw,
                      const float* __restrict__ head_w1, const float* __restrict__ head_b1,
                      const float* __restrict__ head_bn_g, const float* __restrict__ head_bn_b,
                      const float* __restrict__ head_w2, const float* __restrict__ head_b2,
                      float* __restrict__ out)
{
    const int b   = blockIdx.x;
    const int tid = threadIdx.x;

    __shared__ __align__(16) float S[7796];

    float* s_hidden = S;
    float* s_red    = S + 64;
    float* s_q      = S + 96;
    float* featU    = S + FTW;
    float* s_U      = S + FTW;      // gates overwrite featU AFTER proj1 (R4 invariant)

    const float BN_RSQ = 0.9999950000374997f;     // 1/sqrt(1+1e-5)

    // ---------------- stage 0: zeros + weight matrices + flux staging ----------
    featU[tid] = 0.0f;
    if (tid < 4)                    S[tid] = 0.0f;          // fxb el 0..7
    else if (tid < 64)              S[2224 + tid] = 0.0f;   // fxb tail + h1T rows 0..3
    else if (tid < 104)             S[5004 + tid] = 0.0f;   // h1T rows 282..285
    {
        // Wc1[oc][k'] bf16: k'=0 zero, k'=1..15 = sgn*conv1_w[oc][k'-1], 16..31 zero.
        // Sign flip (exact) makes every effective bn1 scale >= 0 so maxpool can
        // run BEFORE the affine (monotone composition).
        const int oc = tid >> 4;
        const int q  = tid & 15;
        const float sgn = (bn1_g[oc] >= 0.0f) ? 1.0f : -1.0f;
        const int k0 = 2 * q, k1 = 2 * q + 1;
        const short e0 = (k0 >= 1 && k0 <= 15) ? f2bf(sgn * conv1_w[oc * 15 + k0 - 1]) : (short)0;
        const short e1 = (k1 <= 15)            ? f2bf(sgn * conv1_w[oc * 15 + k1 - 1]) : (short)0;
        const unsigned pk = (unsigned short)e0 | ((unsigned)(unsigned short)e1 << 16);
        *(unsigned*)((short*)S + WC1_EL + oc * 32 + 2 * q) = pk;
    }
    {
        // Wb[oc][K'=k*16+ic] bf16, row stride 136; k==7 row is the zero pad.
        const int oc = tid >> 3;
        const int k  = tid & 7;
        short tmp[16];
        #pragma unroll
        for (int ic = 0; ic < 16; ++ic)
            tmp[ic] = (k < 7) ? f2bf(conv2_w[oc * 112 + ic * 7 + k]) : (short)0;
        short8 w0, w1;
        #pragma unroll
        for (int e = 0; e < 8; ++e) { w0[e] = tmp[e]; w1[e] = tmp[8 + e]; }
        short8* dst = (short8*)((char*)S + (WB_EL + oc * 136 + k * 16) * 2);
        dst[0] = w0; dst[1] = w1;
    }
    {
        // flux -> bf16 LDS (el x+8): 8 els per iteration, b128 stores.
        const float4* fg = (const float4*)(flux + (size_t)b * L0);
        short* fx = (short*)S;
        for (int t = tid; t < 556; t += 256) {
            float4 v0 = fg[2 * t], v1 = fg[2 * t + 1];
            *(short8*)(fx + 8 + 8 * t) = pack8(v0, v1);
        }
    }
    __syncthreads();

    // ---------------- stage 1: conv1 as MFMA (transposed D) + pool + bn --------
    // (R9-verified) D[j][oc] = X^T[16 j][32 k'] x Wc1^T[32][16 oc].
    {
        const int lane = tid & 63;
        const int wid  = tid >> 6;
        const int col  = lane & 15;
        const int quad = lane >> 4;
        const short* fx = (const short*)S;
        const short8 wfrag = *(const short8*)((const short*)S + WC1_EL + col * 32 + quad * 8);
        const float gsc = fabsf(bn1_g[col]) * BN_RSQ;
        const float gbt = bn1_b[col];

        for (int nt = wid; nt < 70; nt += 4) {
            const int jl = nt * 16 + col;          // A's m-row = conv position
            FragU xu;
            xu.h[0] = *(const short4v*)(fx + 4 * jl + quad * 8);
            xu.h[1] = *(const short4v*)(fx + 4 * jl + quad * 8 + 4);
            f32x4 acc = {0.f, 0.f, 0.f, 0.f};
            acc = __builtin_amdgcn_mfma_f32_16x16x32_bf16(xu.v, wfrag, acc, 0, 0, 0);
            const float m = fmaxf(fmaxf(acc[0], acc[1]), fmaxf(acc[2], acc[3]));
            const int p = nt * 4 + quad;           // pooled position
            if (p < L1P) {
                *((short*)S + H1T_EL + (4 + p) * 20 + col) =
                    f2bf(fmaxf(m * gsc + gbt, 0.0f));
            }
        }
    }
    __syncthreads();   // h1T complete; featU still pure pool sums

    // ---------------- stage 2: conv2 as MFMA (transposed D) + bn/relu + pool ----
    // (R9/R12-verified) D[j][oc] = X^T[144 j][128] x Wb^T[128][32 oc];
    // weight fragments hoisted (nt-invariant).
    {
        const int lane = tid & 63;
        const int wid  = tid >> 6;
        const int col  = lane & 15;
        const int quad = lane >> 4;
        const short* h1s = (const short*)S + H1T_EL;
        const char*  wbc = (const char*)((const short*)S + WB_EL);
        const float sc0 = bn2_g[col] * BN_RSQ,      bt0 = bn2_b[col];
        const float sc1 = bn2_g[col + 16] * BN_RSQ, bt1 = bn2_b[col + 16];

        short8 wa0[4], wa1[4];
        #pragma unroll
        for (int kb = 0; kb < 4; ++kb) {
            wa0[kb] = *(const short8*)(wbc + (col * 136        + kb*32 + quad*8) * 2);
            wa1[kb] = *(const short8*)(wbc + ((16 + col) * 136 + kb*32 + quad*8) * 2);
        }

        for (int nt = wid; nt < 9; nt += 4) {
            const int n0 = nt * 16;
            f32x4 acc0 = {0.f,0.f,0.f,0.f}, acc1 = {0.f,0.f,0.f,0.f};
            #pragma unroll
            for (int kb = 0; kb < 4; ++kb) {
                const int k   = 2 * kb + (quad >> 1);
                const int ic0 = (quad & 1) * 8;
                const int row = 2 * (n0 + col) + 1 + k;
                FragU bu;
                bu.h[0] = *(const short4v*)(h1s + row * 20 + ic0);
                bu.h[1] = *(const short4v*)(h1s + row * 20 + ic0 + 4);
                acc0 = __builtin_amdgcn_mfma_f32_16x16x32_bf16(bu.v, wa0[kb], acc0, 0, 0, 0);
                acc1 = __builtin_amdgcn_mfma_f32_16x16x32_bf16(bu.v, wa1[kb], acc1, 0, 0, 0);
            }
            const int   bA  = (8 * n0) / 139;
            const int   sB  = (139 * (bA + 1)) >> 3;      // j<=sB -> bA; j>=sB -> bA+1
            const float rcA = (bA == 2 || bA == 5) ? (1.0f/19.0f) : (1.0f/18.0f);
            const float rcB = (bA == 1 || bA == 4) ? (1.0f/19.0f) : (1.0f/18.0f);
            float va0 = 0.f, vb0 = 0.f, va1 = 0.f, vb1 = 0.f;
            #pragma unroll
            for (int r = 0; r < 4; ++r) {
                const int j = n0 + quad * 4 + r;
                float v0 = fmaxf(acc0[r] * sc0 + bt0, 0.0f);
                float v1 = fmaxf(acc1[r] * sc1 + bt1, 0.0f);
                if (j > 138) { v0 = 0.0f; v1 = 0.0f; }
                if (j <= sB) { va0 += v0; va1 += v1; }
                if (j >= sB) { vb0 += v0; vb1 += v1; }
            }
            va0 += __shfl_xor(va0, 16, 64); va0 += __shfl_xor(va0, 32, 64);
            va1 += __shfl_xor(va1, 16, 64); va1 += __shfl_xor(va1, 32, 64);
            vb0 += __shfl_xor(vb0, 16, 64); vb0 += __shfl_xor(vb0, 32, 64);
            vb1 += __shfl_xor(vb1, 16, 64); vb1 += __shfl_xor(vb1, 32, 64);
            if (quad == 0) {
                atomicAdd(&featU[col * 8 + bA],        va0 * rcA);
                atomicAdd(&featU[(col + 16) * 8 + bA], va1 * rcA);
                if (bA < 7) {
                    atomicAdd(&featU[col * 8 + bA + 1],        vb0 * rcB);
                    atomicAdd(&featU[(col + 16) * 8 + bA + 1], vb1 * rcB);
                }
            }
        }
    }
    __syncthreads();

    // ---------------- proj1 (256 -> 64), relu ----------------
    {
        const int o = tid >> 2, s = tid & 3;
        const float4* wg = (const float4*)(proj_w1 + 64 * tid);   // == o*256 + s*64
        const float4* xf = (const float4*)(featU + 64 * s);
        float acc = 0.0f;
        #pragma unroll
        for (int t = 0; t < 16; ++t) {
            float4 w4 = wg[t], x4 = xf[t];
            acc += w4.x * x4.x + w4.y * x4.y + w4.z * x4.z + w4.w * x4.w;
        }
        acc += __shfl_down(acc, 2, 64);
        acc += __shfl_down(acc, 1, 64);
        if (s == 0) s_hidden[o] = fmaxf(acc + proj_b1[o], 0.0f);
    }
    __syncthreads();

    // gate matrices into featU (feat consumed — only safe place, R4 invariant);
    // published by the __syncthreads() inside the normalize sequence below.
    if (tid < NL * NQ) {
        float phi = qw[tid * 3 + 0], th = qw[tid * 3 + 1], om = qw[tid * 3 + 2];
        float ch = cosf(0.5f * th), sh = sinf(0.5f * th);
        float a  = 0.5f * (phi + om), bb = 0.5f * (phi - om);
        float ca = cosf(a), sa = sinf(a), cb = cosf(bb), sb = sinf(bb);
        float* U = &s_U[tid * 8];
        U[0] =  ca * ch; U[1] = -sa * ch;   // U00
        U[2] = -cb * sh; U[3] = -sb * sh;   // U01
        U[4] =  cb * sh; U[5] = -sb * sh;   // U10
        U[6] =  ca * ch; U[7] =  sa * ch;   // U11
    }

    // ---------------- proj2 (64 -> 256) + L2 normalize ----------------
    float re;
    {
        const float4* wg = (const float4*)(proj_w2 + 64 * tid);
        const float4* hf = (const float4*)s_hidden;
        float acc = proj_b2[tid];
        #pragma unroll
        for (int t = 0; t < 16; ++t) {
            float4 w4 = wg[t], x4 = hf[t];
            acc += w4.x * x4.x + w4.y * x4.y + w4.z * x4.z + w4.w * x4.w;
        }
        float ss = acc * acc;
        #pragma unroll
        for (int off = 32; off >= 1; off >>= 1) ss += __shfl_xor(ss, off, 64);
        if ((tid & 63) == 0) s_red[tid >> 6] = ss;
        __syncthreads();                           // also publishes s_U
        float sst = s_red[0] + s_red[1] + s_red[2] + s_red[3];
        float n   = sqrtf(sst);
        float inv = 1.0f / fmaxf(n, 1e-12f);
        float xi  = acc * inv;
        if (n * inv < 1e-8f) xi = 0.0625f;        // uniform 1/sqrt(256)
        re = xi;                                   // initial state is real (im = 0)
    }

    // ---------------- publish amplitudes; single barrier; wave-0 tail ----------
    float* areb = S + 256;     // 256-amp re buffer / perm scratch
    float* aimb = S + 512;     // 256-amp im buffer / perm scratch
    areb[tid] = re;
    __syncthreads();           // last barrier: amps + s_U visible to wave 0

    // R13: the whole circuit+Walsh+head runs in wave 0 with 4 amps/lane
    // (amp index bits 6,7 = register index). q=0,1 gates are register-local;
    // q=2..7 are lane shuffles; the CNOT permutation and the tiny s_q handoff
    // use intra-wave LDS (program-ordered, no barrier). Waves 1-3 exit early.
    if (tid < 64) {
        const int lane = tid;
        const int sPl  = permsrc(lane);
        float xr[4], xi4[4];
        #pragma unroll
        for (int r = 0; r < 4; ++r) { xr[r] = areb[64 * r + lane]; xi4[r] = 0.0f; }

        #pragma unroll
        for (int l = 0; l < NL; ++l) {
            // q=0: gate on bit7 -> register pairs (r, r^2)
            {
                const float* U = &s_U[(l * NQ + 0) * 8];
                #pragma unroll
                for (int b6 = 0; b6 < 2; ++b6) {
                    const float i0r = xr[b6],      i0i = xi4[b6];
                    const float i1r = xr[2 + b6],  i1i = xi4[2 + b6];
                    xr[b6]      = U[0]*i0r - U[1]*i0i + U[2]*i1r - U[3]*i1i;
                    xi4[b6]     = U[0]*i0i + U[1]*i0r + U[2]*i1i + U[3]*i1r;
                    xr[2 + b6]  = U[4]*i0r - U[5]*i0i + U[6]*i1r - U[7]*i1i;
                    xi4[2 + b6] = U[4]*i0i + U[5]*i0r + U[6]*i1i + U[7]*i1r;
                }
            }
            // q=1: gate on bit6 -> register pairs (r, r^1)
            {
                const float* U = &s_U[(l * NQ + 1) * 8];
                #pragma unroll
                for (int b7 = 0; b7 < 2; ++b7) {
                    const int r0 = 2 * b7;
                    const float i0r = xr[r0],      i0i = xi4[r0];
                    const float i1r = xr[r0 + 1],  i1i = xi4[r0 + 1];
                    xr[r0]      = U[0]*i0r - U[1]*i0i + U[2]*i1r - U[3]*i1i;
                    xi4[r0]     = U[0]*i0i + U[1]*i0r + U[2]*i1i + U[3]*i1r;
                    xr[r0 + 1]  = U[4]*i0r - U[5]*i0i + U[6]*i1r - U[7]*i1i;
                    xi4[r0 + 1] = U[4]*i0i + U[5]*i0r + U[6]*i1i + U[7]*i1r;
                }
            }
            // q=2..7: lane-bit gates via shuffles, applied to all 4 regs
            #pragma unroll
            for (int q = 2; q < NQ; ++q) {
                const float* U = &s_U[(l * NQ + q) * 8];
                const int bp = 7 - q;
                const int bit = (lane >> bp) & 1;
                const float csr = bit ? U[6] : U[0];
                const float csi = bit ? U[7] : U[1];
                const float cpr = bit ? U[4] : U[2];
                const float cpi = bit ? U[5] : U[3];
                #pragma unroll
                for (int r = 0; r < 4; ++r) {
                    const float pr_ = __shfl_xor(xr[r],  1 << bp, 64);
                    const float pi_ = __shfl_xor(xi4[r], 1 << bp, 64);
                    const float nr = csr * xr[r]  - csi * xi4[r] + cpr * pr_ - cpi * pi_;
                    const float ni = csr * xi4[r] + csi * xr[r]  + cpr * pi_ + cpi * pr_;
                    xr[r] = nr; xi4[r] = ni;
                }
            }
            // CNOT-ring permutation via intra-wave LDS scratch (no barrier):
            // target amp 64r+lane sources permsrc(64r+lane) = sPl ^ {0,P40,P80,PC0}[r]
            #pragma unroll
            for (int r = 0; r < 4; ++r) {
                areb[64 * r + lane] = xr[r];
                aimb[64 * r + lane] = xi4[r];
            }
            const int s0 = sPl, s1 = sPl ^ P40, s2 = sPl ^ P80, s3 = sPl ^ PC0;
            xr[0] = areb[s0]; xi4[0] = aimb[s0];
            xr[1] = areb[s1]; xi4[1] = aimb[s1];
            xr[2] = areb[s2]; xi4[2] = aimb[s2];
            xr[3] = areb[s3]; xi4[3] = aimb[s3];
        }

        // Walsh-Hadamard Z expectations: bits 6,7 = register sign-combines,
        // bits 0..5 = 6-stage lane butterfly (R10-verified mapping).
        const float pr0 = xr[0]*xr[0] + xi4[0]*xi4[0];
        const float pr1 = xr[1]*xr[1] + xi4[1]*xi4[1];
        const float pr2 = xr[2]*xr[2] + xi4[2]*xi4[2];
        const float pr3 = xr[3]*xr[3] + xi4[3]*xi4[3];
        float t  = pr0 + pr1 + pr2 + pr3;
        float u6 = pr0 - pr1 + pr2 - pr3;   // sign = bit6 = r&1
        float u7 = pr0 + pr1 - pr2 - pr3;   // sign = bit7 = r>>1
        #pragma unroll
        for (int d = 0; d < 6; ++d) {
            const float p = __shfl_xor(t, 1 << d, 64);
            t = ((lane >> d) & 1) ? (p - t) : (t + p);
            u6 += __shfl_xor(u6, 1 << d, 64);
            u7 += __shfl_xor(u7, 1 << d, 64);
        }
        if (lane == 0) { s_q[0] = u7; s_q[1] = u6; }
        else if ((lane & (lane - 1)) == 0) {
            const int bp = 31 - __clz(lane);          // lane = 1<<bp, bp in 1..5? no: 0..5
            s_q[7 - bp] = t;                          // <Z_q> with q = 7-bp
        }
        // head layer 1 (lanes 0..31; s_q read-after-write, same wave)
        float h = 0.0f;
        if (lane < 32) {
            float acc = head_b1[lane];
            #pragma unroll
            for (int k = 0; k < 8; ++k) acc += head_w1[lane * 14 + k] * s_q[k];
            #pragma unroll
            for (int k = 0; k < 6; ++k) acc += head_w1[lane * 14 + 8 + k] * scalars[b * 6 + k];
            h = fmaxf(acc * (head_bn_g[lane] * BN_RSQ) + head_bn_b[lane], 0.0f);
        }
        // head layer 2: 3 dot-products over 32 h values via butterfly reduce
        float p0 = (lane < 32) ? h * head_w2[lane]      : 0.0f;
        float p1 = (lane < 32) ? h * head_w2[32 + lane] : 0.0f;
        float p2 = (lane < 32) ? h * head_w2[64 + lane] : 0.0f;
        #pragma unroll
        for (int d = 0; d < 6; ++d) {
            p0 += __shfl_xor(p0, 1 << d, 64);
            p1 += __shfl_xor(p1, 1 << d, 64);
            p2 += __shfl_xor(p2, 1 << d, 64);
        }
        if (lane < 3) {
            const float v = (lane == 0) ? p0 : ((lane == 1) ? p1 : p2);
            out[b * 3 + lane] = v + head_b2[lane];
        }
    }
}

extern "C" void kernel_launch(void* const* d_in, const int* in_sizes, int n_in,
                              void* d_out, int out_size, void* d_ws, size_t ws_size,
                              hipStream_t stream) {
    const float* flux      = (const float*)d_in[0];
    const float* scalars   = (const float*)d_in[1];
    const float* conv1_w   = (const float*)d_in[2];
    const float* bn1_g     = (const float*)d_in[3];
    const float* bn1_b     = (const float*)d_in[4];
    const float* conv2_w   = (const float*)d_in[5];
    const float* bn2_g     = (const float*)d_in[6];
    const float* bn2_b     = (const float*)d_in[7];
    const float* proj_w1   = (const float*)d_in[8];
    const float* proj_b1   = (const float*)d_in[9];
    const float* proj_w2   = (const float*)d_in[10];
    const float* proj_b2   = (const float*)d_in[11];
    const float* q_weights = (const float*)d_in[12];
    const float* head_w1   = (const float*)d_in[13];
    const float* head_b1   = (const float*)d_in[14];
    const float* head_bn_g = (const float*)d_in[15];
    const float* head_bn_b = (const float*)d_in[16];
    const float* head_w2   = (const float*)d_in[17];
    const float* head_b2   = (const float*)d_in[18];

    const int B = in_sizes[0] / L0;   // 4096

    aec_fused_kernel<<<dim3(B), dim3(256), 0, stream>>>(
        flux, scalars, conv1_w, bn1_g, bn1_b, conv2_w, bn2_g, bn2_b,
        proj_w1, proj_b1, proj_w2, proj_b2, q_weights,
        head_w1, head_b1, head_bn_g, head_bn_b, head_w2, head_b2,
        (float*)d_out);
}